// Round 18
// baseline (323.769 us; speedup 1.0000x reference)
//
#include <hip/hip_runtime.h>
#include <hip/hip_bf16.h>

typedef __bf16 bf16;
typedef __bf16 bf16x4 __attribute__((ext_vector_type(4)));
typedef __bf16 bf16x8 __attribute__((ext_vector_type(8)));
typedef float f32x4 __attribute__((ext_vector_type(4)));
typedef float floatv4 __attribute__((ext_vector_type(4)));

#define QK_SCALE 0.17677669529663687f

// ---- LDS addressing ----------------------------------------------------------
// x/ao tile [49][192], XOR swizzle: chunk ^= row&7 within each 8-chunk group.
__device__ __forceinline__ bf16* t192_ptr(bf16* base, int row, int col) {
    return base + row * 192 + ((((col >> 3) ^ (row & 7)) << 3)) + (col & 7);
}
// q/k tiles [50][32] (row 49 = clamp scratch), XOR swizzle.
__device__ __forceinline__ bf16* qk_ptr(bf16* base, int row, int col) {
    return base + row * 32 + ((((col >> 3) ^ ((row >> 1) & 3)) << 3)) + (col & 7);
}
// vt tile [32][56] affine: row stride 112 B -> bank step -4 mod 32 -> 2-way max.
__device__ __forceinline__ bf16* vt_ptr(bf16* base, int row, int col) {
    return base + row * 56 + col;
}

// ---------------- prep: weight bf16 convert + rpb expand + combo table --------
__global__ void wmsa_prep(const float* __restrict__ qkv_w,
                          const float* __restrict__ out_w,
                          const float* __restrict__ rpb_table,
                          const float* __restrict__ mask,
                          bf16* __restrict__ qkv_wb,
                          bf16* __restrict__ out_wb,
                          float* __restrict__ rpbx,
                          float* __restrict__ combo,
                          int build_combo) {
    int t = blockIdx.x * 256 + threadIdx.x;
    if (t < 110592) qkv_wb[t] = (bf16)qkv_w[t];
    if (t < 36864)  out_wb[t] = (bf16)out_w[t];
    if (t < 14406) {
        int h = t / 2401, ij = t % 2401, i = ij / 49, j = ij % 49;
        int ri = (i / 7 - j / 7 + 6) * 13 + (i % 7 - j % 7 + 6);
        rpbx[t] = rpb_table[ri * 6 + h];
    }
    if (build_combo && t < 64 * 6 * 64 * 64) {
        int j = t & 63, i = (t >> 6) & 63, r = t >> 12;
        int h = r % 6, w = r / 6;
        float v = -1e30f;
        if (i < 49 && j < 49) {
            int ri = (i / 7 - j / 7 + 6) * 13 + (i % 7 - j % 7 + 6);
            v = rpb_table[ri * 6 + h] + mask[w * 2401 + i * 49 + j];
        }
        combo[t] = v;
    }
}

// ========== fused kernel: one window per 384-thread block, 2 blocks/CU ========
// LDS 78720 B (2x = 157440 < 160 KiB with slack). Phase bodies = r15 per-pass
// structure, looped; phase 2 fully decoupled (ao -> dead s_x rows 0..48).
template <bool USE_COMBO>
__global__ __launch_bounds__(384, 3) void wmsa_fused(
    const float* __restrict__ x, const float* __restrict__ mask,
    const float* __restrict__ qkv_b, const float* __restrict__ out_b,
    const bf16* __restrict__ qkv_wb, const bf16* __restrict__ out_wb,
    const float* __restrict__ rpbx, const float* __restrict__ combo,
    float* __restrict__ out)
{
    __shared__ __align__(16) bf16 s_lds[39360];   // 78720 B
    bf16* s_x  = s_lds;            // [49][192] swz: x, then ao rows 0..48
    bf16* s_q  = s_lds + 9408;     // 6 x [50][32] swz (row 49 scratch)
    bf16* s_k  = s_lds + 19008;    // 6 x [50][32] swz
    bf16* s_vt = s_lds + 28608;    // 6 x [32][56] affine

    const int b    = blockIdx.x;
    const int tid  = threadIdx.x;
    const int wv   = tid >> 6;      // 0..5
    const int lane = tid & 63;
    const int lo   = lane & 15;
    const int hi   = lane >> 4;     // 0..3

    const float* xw  = x + (size_t)b * 9408;
    const int    sec = wv >> 1;     // 0=q 1=k 2=v (uniform per wave)

    // ============ Phase 0: stage x (fp32 -> bf16) into LDS [49][192] ==========
#pragma unroll
    for (int q2 = 0; q2 < 4; ++q2) {
        const int gc = q2 * 384 + tid;            // 0..1175 16B chunks
        if (gc < 1176) {
            const int rs = gc / 24, cc = gc % 24;
            const float* p = xw + rs * 192 + cc * 8;
            floatv4 f0 = *(const floatv4*)p;
            floatv4 f1 = *(const floatv4*)(p + 4);
            bf16x8 v;
            v[0]=(bf16)f0[0]; v[1]=(bf16)f0[1]; v[2]=(bf16)f0[2]; v[3]=(bf16)f0[3];
            v[4]=(bf16)f1[0]; v[5]=(bf16)f1[1]; v[6]=(bf16)f1[2]; v[7]=(bf16)f1[3];
            *(bf16x8*)&s_x[(rs * 24 + (cc ^ (rs & 7))) * 8] = v;
        }
    }
    __syncthreads();                               // barrier 1: x visible

    // ============ Phase 1: QKV, two 48-col halves per wave ====================
#pragma unroll 1
    for (int nj2 = 0; nj2 < 2; ++nj2) {
        const int colbase = wv * 96 + nj2 * 48;
#pragma unroll 1
        for (int mib = 0; mib < 2; ++mib) {
            f32x4 acc[2][3];
#pragma unroll
            for (int mi = 0; mi < 2; ++mi)
#pragma unroll
                for (int nj = 0; nj < 3; ++nj) acc[mi][nj] = (f32x4){0.f, 0.f, 0.f, 0.f};

            const int r0 = mib * 32 + lo;          // <= 47
            const int r1 = min(r0 + 16, 48);       // rows >=49 read row 48 (discarded)

            auto loadB = [&](bf16x8* dst, int kk) {
#pragma unroll
                for (int nj = 0; nj < 3; ++nj)
                    dst[nj] = *(const bf16x8*)(qkv_wb + (colbase + nj * 16 + lo) * 192 + kk * 32 + hi * 8);
            };

            bf16x8 b0_[3], b1_[3], b2_[3];
            loadB(b0_, 0);
            loadB(b1_, 1);
#pragma unroll
            for (int kk = 0; kk < 6; ++kk) {
                if (kk < 4) loadB(b2_, kk + 2);
                bf16x8 a0 = *(const bf16x8*)t192_ptr(s_x, r0, kk * 32 + hi * 8);
                bf16x8 a1 = *(const bf16x8*)t192_ptr(s_x, r1, kk * 32 + hi * 8);
                acc[0][0] = __builtin_amdgcn_mfma_f32_16x16x32_bf16(a0, b0_[0], acc[0][0], 0, 0, 0);
                acc[1][0] = __builtin_amdgcn_mfma_f32_16x16x32_bf16(a1, b0_[0], acc[1][0], 0, 0, 0);
                acc[0][1] = __builtin_amdgcn_mfma_f32_16x16x32_bf16(a0, b0_[1], acc[0][1], 0, 0, 0);
                acc[1][1] = __builtin_amdgcn_mfma_f32_16x16x32_bf16(a1, b0_[1], acc[1][1], 0, 0, 0);
                acc[0][2] = __builtin_amdgcn_mfma_f32_16x16x32_bf16(a0, b0_[2], acc[0][2], 0, 0, 0);
                acc[1][2] = __builtin_amdgcn_mfma_f32_16x16x32_bf16(a1, b0_[2], acc[1][2], 0, 0, 0);
                b0_[0] = b1_[0]; b0_[1] = b1_[1]; b0_[2] = b1_[2];
                b1_[0] = b2_[0]; b1_[1] = b2_[1]; b1_[2] = b2_[2];
            }

            // epilogue: bias + scatter into q / k / v^T LDS tiles (row clamps)
            if (sec < 2) {
#pragma unroll
                for (int nj = 0; nj < 3; ++nj) {
                    const int o    = colbase + nj * 16 + lo;
                    const float bs = qkv_b[o];
                    const int oc   = o - sec * 192;
                    const int hh   = oc >> 5;
                    const int dd   = oc & 31;
                    bf16* base = (sec == 0) ? (s_q + hh * 1600) : (s_k + hh * 1600);
#pragma unroll
                    for (int mi = 0; mi < 2; ++mi)
#pragma unroll
                        for (int r = 0; r < 4; ++r) {
                            const int n  = mib * 32 + mi * 16 + hi * 4 + r;
                            const int nc = min(n, 49);           // 49 = scratch row
                            const float v = acc[mi][nj][r] + bs;
                            *qk_ptr(base, nc, dd) = (sec == 0) ? (bf16)(v * QK_SCALE) : (bf16)v;
                        }
                }
            } else {
#pragma unroll
                for (int nj = 0; nj < 3; ++nj) {
                    const int o    = colbase + nj * 16 + lo;
                    const float bs = qkv_b[o];
                    const int oc   = o - 384;
                    const int hh   = oc >> 5;
                    const int dd   = oc & 31;
#pragma unroll
                    for (int mi = 0; mi < 2; ++mi) {
                        const int n0 = mib * 32 + mi * 16 + hi * 4;
                        if (n0 < 56) {                           // vt has 56 cols
                            bf16x4 pk;
#pragma unroll
                            for (int r = 0; r < 4; ++r) pk[r] = (bf16)(acc[mi][nj][r] + bs);
                            *(bf16x4*)vt_ptr(s_vt + hh * 1792, dd, n0) = pk;
                        }
                    }
                }
            }
        }
    }
    __syncthreads();                               // barrier 2: q/k/vt visible

    // ====== Phase 2: attention, head = wave, two 32-row passes, decoupled =====
    {
        const int h = wv;
        bf16* qb    = s_q + h * 1600;
        bf16* kbase = s_k + h * 1600;
        bf16* vtb   = s_vt + h * 1792;

#pragma unroll 1
        for (int p = 0; p < 2; ++p) {
            const int arow = p * 32;

            // combo loads: one floatv4 per (mi,nt)
            f32x4 cv[2][4];
            if (USE_COMBO) {
                const float* cb = combo + (((size_t)(b & 63) * 6 + h) << 12);
#pragma unroll
                for (int mi = 0; mi < 2; ++mi) {
                    const int i = arow + mi * 16 + lo;
#pragma unroll
                    for (int nt = 0; nt < 4; ++nt)
                        cv[mi][nt] = *(const floatv4*)(cb + i * 64 + nt * 16 + hi * 4);
                }
            }

            bf16x8 qa0 = *(const bf16x8*)qk_ptr(qb, arow + lo, hi * 8);
            bf16x8 qa1 = *(const bf16x8*)qk_ptr(qb, min(arow + 16 + lo, 49), hi * 8);
            bf16x8 kb0 = *(const bf16x8*)qk_ptr(kbase,  0 + lo, hi * 8);
            bf16x8 kb1 = *(const bf16x8*)qk_ptr(kbase, 16 + lo, hi * 8);
            bf16x8 kb2 = *(const bf16x8*)qk_ptr(kbase, 32 + lo, hi * 8);
            bf16x8 kb3 = *(const bf16x8*)qk_ptr(kbase, min(48 + lo, 49), hi * 8);

            // S^T = mfma(K, Q): col i = arow+mi*16+lo, row j = nt*16+hi*4+r
            f32x4 t[4][2];
#pragma unroll
            for (int nt = 0; nt < 4; ++nt)
#pragma unroll
                for (int mi = 0; mi < 2; ++mi) t[nt][mi] = (f32x4){0.f, 0.f, 0.f, 0.f};
            t[0][0] = __builtin_amdgcn_mfma_f32_16x16x32_bf16(kb0, qa0, t[0][0], 0, 0, 0);
            t[1][0] = __builtin_amdgcn_mfma_f32_16x16x32_bf16(kb1, qa0, t[1][0], 0, 0, 0);
            t[2][0] = __builtin_amdgcn_mfma_f32_16x16x32_bf16(kb2, qa0, t[2][0], 0, 0, 0);
            t[3][0] = __builtin_amdgcn_mfma_f32_16x16x32_bf16(kb3, qa0, t[3][0], 0, 0, 0);
            t[0][1] = __builtin_amdgcn_mfma_f32_16x16x32_bf16(kb0, qa1, t[0][1], 0, 0, 0);
            t[1][1] = __builtin_amdgcn_mfma_f32_16x16x32_bf16(kb1, qa1, t[1][1], 0, 0, 0);
            t[2][1] = __builtin_amdgcn_mfma_f32_16x16x32_bf16(kb2, qa1, t[2][1], 0, 0, 0);
            t[3][1] = __builtin_amdgcn_mfma_f32_16x16x32_bf16(kb3, qa1, t[3][1], 0, 0, 0);

            if (USE_COMBO) {
#pragma unroll
                for (int mi = 0; mi < 2; ++mi)
#pragma unroll
                    for (int nt = 0; nt < 4; ++nt) t[nt][mi] += cv[mi][nt];
            } else {
                const float* mk = mask + (size_t)(b & 63) * 2401;
                const float* rb = rpbx + h * 2401;
#pragma unroll
                for (int nt = 0; nt < 4; ++nt)
#pragma unroll
                    for (int mi = 0; mi < 2; ++mi)
#pragma unroll
                        for (int r = 0; r < 4; ++r) {
                            const int i = arow + mi * 16 + lo;
                            const int j = nt * 16 + hi * 4 + r;
                            float sv = t[nt][mi][r];
                            if (j >= 49 || i >= 49) sv = -1e30f;
                            else sv += rb[i * 49 + j] + mk[i * 49 + j];
                            t[nt][mi][r] = sv;
                        }
            }

            // softmax over j: 16 in-lane + xor16/32
#pragma unroll
            for (int mi = 0; mi < 2; ++mi) {
                float m = t[0][mi][0];
#pragma unroll
                for (int nt = 0; nt < 4; ++nt)
#pragma unroll
                    for (int r = 0; r < 4; ++r) m = fmaxf(m, t[nt][mi][r]);
                m = fmaxf(m, __shfl_xor(m, 16));
                m = fmaxf(m, __shfl_xor(m, 32));
                float sum = 0.f;
#pragma unroll
                for (int nt = 0; nt < 4; ++nt)
#pragma unroll
                    for (int r = 0; r < 4; ++r) {
                        float pv = __expf(t[nt][mi][r] - m);
                        t[nt][mi][r] = pv;
                        sum += pv;
                    }
                sum += __shfl_xor(sum, 16);
                sum += __shfl_xor(sum, 32);
                const float inv = 1.0f / sum;
#pragma unroll
                for (int nt = 0; nt < 4; ++nt)
#pragma unroll
                    for (int r = 0; r < 4; ++r) t[nt][mi][r] *= inv;
            }

            // PV swapped: O^T = mfma(V^T, P); P staged bf16x4 into own q rows
            f32x4 o00 = (f32x4){0.f,0.f,0.f,0.f}, o01 = (f32x4){0.f,0.f,0.f,0.f};
            f32x4 o10 = (f32x4){0.f,0.f,0.f,0.f}, o11 = (f32x4){0.f,0.f,0.f,0.f};
#pragma unroll
            for (int kk = 0; kk < 2; ++kk) {
#pragma unroll
                for (int mi = 0; mi < 2; ++mi)
#pragma unroll
                    for (int c = 0; c < 2; ++c) {
                        const int nt = kk * 2 + c;
                        bf16x4 pk;
#pragma unroll
                        for (int r = 0; r < 4; ++r) pk[r] = (bf16)t[nt][mi][r];
                        *(bf16x4*)qk_ptr(qb, min(arow + mi * 16 + lo, 49), c * 16 + hi * 4) = pk;
                    }
                bf16x8 pa0 = *(const bf16x8*)qk_ptr(qb, arow + lo, hi * 8);
                bf16x8 pa1 = *(const bf16x8*)qk_ptr(qb, min(arow + 16 + lo, 49), hi * 8);
                const int vc = min(kk * 32 + hi * 8, 48);   // cols >=56 -> 48 (P=0 there)
                bf16x8 vb0 = *(const bf16x8*)vt_ptr(vtb,  0 + lo, vc);
                bf16x8 vb1 = *(const bf16x8*)vt_ptr(vtb, 16 + lo, vc);
                o00 = __builtin_amdgcn_mfma_f32_16x16x32_bf16(vb0, pa0, o00, 0, 0, 0);
                o01 = __builtin_amdgcn_mfma_f32_16x16x32_bf16(vb0, pa1, o01, 0, 0, 0);
                o10 = __builtin_amdgcn_mfma_f32_16x16x32_bf16(vb1, pa0, o10, 0, 0, 0);
                o11 = __builtin_amdgcn_mfma_f32_16x16x32_bf16(vb1, pa1, o11, 0, 0, 0);
            }

            // ao writes (rows >=49 dropped; s_x rows 0..48 are dead x)
            {
                bf16x4 w00, w01, w10, w11;
#pragma unroll
                for (int r = 0; r < 4; ++r) {
                    w00[r] = (bf16)o00[r]; w01[r] = (bf16)o01[r];
                    w10[r] = (bf16)o10[r]; w11[r] = (bf16)o11[r];
                }
                const int row0 = arow + lo;            // <= 47
                const int row1 = arow + 16 + lo;       // <= 63
                *(bf16x4*)t192_ptr(s_x, row0, h * 32 +  0 + hi * 4) = w00;
                *(bf16x4*)t192_ptr(s_x, row0, h * 32 + 16 + hi * 4) = w10;
                if (row1 < 49) {
                    *(bf16x4*)t192_ptr(s_x, row1, h * 32 +  0 + hi * 4) = w01;
                    *(bf16x4*)t192_ptr(s_x, row1, h * 32 + 16 + hi * 4) = w11;
                }
            }
        }
    }
    __syncthreads();                               // barrier 3: ao visible

    // ============ Phase 3: out = ao @ out_w^T + out_b, two 16-col tiles =======
#pragma unroll 1
    for (int t2 = 0; t2 < 2; ++t2) {
        const int o2 = wv * 32 + t2 * 16 + lo;     // 0..191
        f32x4 facc[4];
#pragma unroll
        for (int mi = 0; mi < 4; ++mi) facc[mi] = (f32x4){0.f, 0.f, 0.f, 0.f};

        bf16x8 fbc = *(const bf16x8*)(out_wb + o2 * 192 + hi * 8);
#pragma unroll
        for (int kk = 0; kk < 6; ++kk) {
            bf16x8 fbn;
            if (kk < 5) fbn = *(const bf16x8*)(out_wb + o2 * 192 + (kk + 1) * 32 + hi * 8);
            bf16x8 fa[4];
#pragma unroll
            for (int mi = 0; mi < 4; ++mi)
                fa[mi] = *(const bf16x8*)t192_ptr(s_x, mi * 16 + lo, kk * 32 + hi * 8);
            // rows >=49 read past the x tile into s_q (finite garbage; outputs dropped)
#pragma unroll
            for (int mi = 0; mi < 4; ++mi)
                facc[mi] = __builtin_amdgcn_mfma_f32_16x16x32_bf16(fa[mi], fbc, facc[mi], 0, 0, 0);
            fbc = fbn;
        }

        const float ob = out_b[o2];
        float* ow = out + (size_t)b * 9408;
#pragma unroll
        for (int mi = 0; mi < 4; ++mi)
#pragma unroll
            for (int r = 0; r < 4; ++r) {
                const int n = mi * 16 + hi * 4 + r;
                if (n < 49) ow[n * 192 + o2] = facc[mi][r] + ob;
            }
    }
}

extern "C" void kernel_launch(void* const* d_in, const int* in_sizes, int n_in,
                              void* d_out, int out_size, void* d_ws, size_t ws_size,
                              hipStream_t stream) {
    const float* x      = (const float*)d_in[0];
    const float* mask   = (const float*)d_in[1];
    const float* qkv_w  = (const float*)d_in[2];
    const float* qkv_b  = (const float*)d_in[3];
    const float* out_w  = (const float*)d_in[4];
    const float* out_b  = (const float*)d_in[5];
    const float* rpb    = (const float*)d_in[6];
    float* out          = (float*)d_out;

    char* ws = (char*)d_ws;
    bf16*  qkv_wb = (bf16*)ws;                       // 110592 * 2 = 221184 B
    bf16*  out_wb = (bf16*)(ws + 221184);            //  36864 * 2 =  73728 B
    float* rpbx   = (float*)(ws + 294912);           //  14406 * 4 =  57624 B
    float* combo  = (float*)(ws + 352768);           // 1572864 * 4 = 6291456 B
    const bool use_combo = ws_size >= (size_t)(352768 + 6291456);

    hipLaunchKernelGGL(wmsa_prep, dim3(6144), dim3(256), 0, stream,
                       qkv_w, out_w, rpb, mask, qkv_wb, out_wb, rpbx, combo,
                       use_combo ? 1 : 0);
    if (use_combo)
        hipLaunchKernelGGL(HIP_KERNEL_NAME(wmsa_fused<true>), dim3(4096), dim3(384), 0, stream,
                           x, mask, qkv_b, out_b, qkv_wb, out_wb, rpbx, combo, out);
    else
        hipLaunchKernelGGL(HIP_KERNEL_NAME(wmsa_fused<false>), dim3(4096), dim3(384), 0, stream,
                           x, mask, qkv_b, out_b, qkv_wb, out_wb, rpbx, combo, out);
}

// Round 19
// 257.684 us; speedup vs baseline: 1.2565x; 1.2565x over previous
//
#include <hip/hip_runtime.h>
#include <hip/hip_bf16.h>

typedef __bf16 bf16;
typedef __bf16 bf16x4 __attribute__((ext_vector_type(4)));
typedef __bf16 bf16x8 __attribute__((ext_vector_type(8)));
typedef float f32x4 __attribute__((ext_vector_type(4)));
typedef float floatv4 __attribute__((ext_vector_type(4)));

#define QK_SCALE 0.17677669529663687f

// ---- padded affine LDS addressing (no XOR swizzle) ---------------------------
#define X_LD 200   // x/ao tile [64][200]
#define QK_LD 40   // q/k tiles [64][40]
#define VT_LD 72   // vt tiles [32][72]

__device__ __forceinline__ bf16* x_ptr(bf16* base, int row, int col) {
    return base + row * X_LD + col;
}
__device__ __forceinline__ bf16* qk_ptr(bf16* base, int row, int col) {
    return base + row * QK_LD + col;
}
__device__ __forceinline__ bf16* vt_ptr(bf16* base, int row, int col) {
    return base + row * VT_LD + col;
}

// ---------------- prep: weight bf16 convert + rpb expand + combo table --------
__global__ void wmsa_prep(const float* __restrict__ qkv_w,
                          const float* __restrict__ out_w,
                          const float* __restrict__ rpb_table,
                          const float* __restrict__ mask,
                          bf16* __restrict__ qkv_wb,
                          bf16* __restrict__ out_wb,
                          float* __restrict__ rpbx,
                          float* __restrict__ combo,
                          int build_combo) {
    int t = blockIdx.x * 256 + threadIdx.x;
    if (t < 110592) qkv_wb[t] = (bf16)qkv_w[t];
    if (t < 36864)  out_wb[t] = (bf16)out_w[t];
    if (t < 14406) {
        int h = t / 2401, ij = t % 2401, i = ij / 49, j = ij % 49;
        int ri = (i / 7 - j / 7 + 6) * 13 + (i % 7 - j % 7 + 6);
        rpbx[t] = rpb_table[ri * 6 + h];
    }
    if (build_combo && t < 64 * 6 * 64 * 64) {
        int j = t & 63, i = (t >> 6) & 63, r = t >> 12;
        int h = r % 6, w = r / 6;
        float v = -1e30f;
        if (i < 49 && j < 49) {
            int ri = (i / 7 - j / 7 + 6) * 13 + (i % 7 - j % 7 + 6);
            v = rpb_table[ri * 6 + h] + mask[w * 2401 + i * 49 + j];
        }
        combo[t] = v;
    }
}

// =================== fused kernel: one window per block, 12 waves =============
// Final form (r15): 3 barriers; phase 2 swapped-operand (S^T, O^T), per-wave
// decoupled; padded affine LDS; all hot stores vectorized.
template <bool USE_COMBO>
__global__ __launch_bounds__(768, 3) void wmsa_fused(
    const float* __restrict__ x, const float* __restrict__ mask,
    const float* __restrict__ qkv_b, const float* __restrict__ out_b,
    const bf16* __restrict__ qkv_wb, const bf16* __restrict__ out_wb,
    const float* __restrict__ rpbx, const float* __restrict__ combo,
    float* __restrict__ out)
{
    __shared__ __align__(16) bf16 s_x[64 * X_LD];     // x [64][200]; later ao
    __shared__ __align__(16) bf16 s_qp[6][64 * QK_LD];// q, then P (per head)
    __shared__ __align__(16) bf16 s_k[6][64 * QK_LD]; // k (per head)
    __shared__ __align__(16) bf16 s_vt[6][32 * VT_LD];// v^T

    const int b    = blockIdx.x;
    const int tid  = threadIdx.x;
    const int wv   = tid >> 6;      // 0..11
    const int lane = tid & 63;
    const int lo   = lane & 15;
    const int hi   = lane >> 4;     // 0..3

    const float* xw    = x + (size_t)b * 9408;
    const int    obase = wv * 48;   // 48 qkv output cols per wave
    const int    sec   = wv >> 2;   // 0=q 1=k 2=v (uniform per wave)

    // ============ Phase 0: stage x (fp32 -> bf16) into LDS, zero-padded =======
    {
        const int c0 = tid;                       // rows 0..31
        const int r0s = c0 / 24, cc0 = c0 % 24;
        const float* p0 = xw + r0s * 192 + cc0 * 8;
        floatv4 f0 = *(const floatv4*)p0;
        floatv4 f1 = *(const floatv4*)(p0 + 4);
        bf16x8 v;
        v[0]=(bf16)f0[0]; v[1]=(bf16)f0[1]; v[2]=(bf16)f0[2]; v[3]=(bf16)f0[3];
        v[4]=(bf16)f1[0]; v[5]=(bf16)f1[1]; v[6]=(bf16)f1[2]; v[7]=(bf16)f1[3];
        *(bf16x8*)&s_x[r0s * X_LD + cc0 * 8] = v;

        const int c1 = tid + 768;                 // rows 32..63 (zero >= 49)
        const int r1s = c1 / 24, cc1 = c1 % 24;
        bf16x8 w = {};
        if (r1s < 49) {
            const float* p1 = xw + r1s * 192 + cc1 * 8;
            floatv4 g0 = *(const floatv4*)p1;
            floatv4 g1 = *(const floatv4*)(p1 + 4);
            w[0]=(bf16)g0[0]; w[1]=(bf16)g0[1]; w[2]=(bf16)g0[2]; w[3]=(bf16)g0[3];
            w[4]=(bf16)g1[0]; w[5]=(bf16)g1[1]; w[6]=(bf16)g1[2]; w[7]=(bf16)g1[3];
        }
        *(bf16x8*)&s_x[r1s * X_LD + cc1 * 8] = w;
    }
    __syncthreads();                               // barrier 1: x visible

    // ============ Phase 1: QKV = x @ qkv_w^T + qkv_b (A from LDS, B 2-deep) ===
#pragma unroll 1
    for (int mib = 0; mib < 2; ++mib) {
        f32x4 acc[2][3];
#pragma unroll
        for (int mi = 0; mi < 2; ++mi)
#pragma unroll
            for (int nj = 0; nj < 3; ++nj) acc[mi][nj] = (f32x4){0.f, 0.f, 0.f, 0.f};

        const int r0 = mib * 32 + lo;
        const int r1 = r0 + 16;        // rows >= 49 are zeros in s_x

        auto loadB = [&](bf16x8* dst, int kk) {
#pragma unroll
            for (int nj = 0; nj < 3; ++nj)
                dst[nj] = *(const bf16x8*)(qkv_wb + (obase + nj * 16 + lo) * 192 + kk * 32 + hi * 8);
        };

        bf16x8 b0_[3], b1_[3], b2_[3];
        loadB(b0_, 0);
        loadB(b1_, 1);
#pragma unroll
        for (int kk = 0; kk < 6; ++kk) {
            if (kk < 4) loadB(b2_, kk + 2);
            bf16x8 a0 = *(const bf16x8*)x_ptr(s_x, r0, kk * 32 + hi * 8);
            bf16x8 a1 = *(const bf16x8*)x_ptr(s_x, r1, kk * 32 + hi * 8);
            acc[0][0] = __builtin_amdgcn_mfma_f32_16x16x32_bf16(a0, b0_[0], acc[0][0], 0, 0, 0);
            acc[1][0] = __builtin_amdgcn_mfma_f32_16x16x32_bf16(a1, b0_[0], acc[1][0], 0, 0, 0);
            acc[0][1] = __builtin_amdgcn_mfma_f32_16x16x32_bf16(a0, b0_[1], acc[0][1], 0, 0, 0);
            acc[1][1] = __builtin_amdgcn_mfma_f32_16x16x32_bf16(a1, b0_[1], acc[1][1], 0, 0, 0);
            acc[0][2] = __builtin_amdgcn_mfma_f32_16x16x32_bf16(a0, b0_[2], acc[0][2], 0, 0, 0);
            acc[1][2] = __builtin_amdgcn_mfma_f32_16x16x32_bf16(a1, b0_[2], acc[1][2], 0, 0, 0);
            b0_[0] = b1_[0]; b0_[1] = b1_[1]; b0_[2] = b1_[2];
            b1_[0] = b2_[0]; b1_[1] = b2_[1]; b1_[2] = b2_[2];
        }

        // epilogue: bias + scatter into q / k / v^T LDS tiles
        if (sec < 2) {
#pragma unroll
            for (int nj = 0; nj < 3; ++nj) {
                const int o    = obase + nj * 16 + lo;
                const float bs = qkv_b[o];
                const int oc   = o - sec * 192;
                const int hh   = oc >> 5;
                const int dd   = oc & 31;
                bf16* base = (sec == 0) ? &s_qp[hh][0] : &s_k[hh][0];
#pragma unroll
                for (int mi = 0; mi < 2; ++mi)
#pragma unroll
                    for (int r = 0; r < 4; ++r) {
                        const int n = mib * 32 + mi * 16 + hi * 4 + r;
                        const float v = acc[mi][nj][r] + bs;
                        *qk_ptr(base, n, dd) = (sec == 0) ? (bf16)(v * QK_SCALE) : (bf16)v;
                    }
            }
        } else {
            // v waves: rows n contiguous in r -> vectorized b64 stores into vt
#pragma unroll
            for (int nj = 0; nj < 3; ++nj) {
                const int o    = obase + nj * 16 + lo;
                const float bs = qkv_b[o];
                const int oc   = o - 384;
                const int hh   = oc >> 5;
                const int dd   = oc & 31;
#pragma unroll
                for (int mi = 0; mi < 2; ++mi) {
                    const int n0 = mib * 32 + mi * 16 + hi * 4;
                    bf16x4 pk;
#pragma unroll
                    for (int r = 0; r < 4; ++r) pk[r] = (bf16)(acc[mi][nj][r] + bs);
                    *(bf16x4*)vt_ptr(&s_vt[hh][0], dd, n0) = pk;
                }
            }
        }
    }
    __syncthreads();                               // barrier 2: q/k/vt visible

    // ====== Phase 2: attention, swapped operands, per-wave decoupled ==========
    {
        const int h    = wv >> 1;    // 0..5
        const int arow = (wv & 1) * 32;
        bf16* qb    = &s_qp[h][0];
        bf16* kbase = &s_k[h][0];

        // combo loads: lane owns col i = arow+mi*16+lo, rows j = nt*16+hi*4+..+3
        // -> one floatv4 per (mi,nt): 8 dwordx4 instead of 32 dword
        f32x4 cv[2][4];
        if (USE_COMBO) {
            const float* cb = combo + (((size_t)(b & 63) * 6 + h) << 12);
#pragma unroll
            for (int mi = 0; mi < 2; ++mi) {
                const int i = arow + mi * 16 + lo;
#pragma unroll
                for (int nt = 0; nt < 4; ++nt)
                    cv[mi][nt] = *(const floatv4*)(cb + i * 64 + nt * 16 + hi * 4);
            }
        }

        bf16x8 qa0 = *(const bf16x8*)qk_ptr(qb, arow + lo, hi * 8);
        bf16x8 qa1 = *(const bf16x8*)qk_ptr(qb, arow + 16 + lo, hi * 8);
        bf16x8 kb0 = *(const bf16x8*)qk_ptr(kbase,  0 + lo, hi * 8);
        bf16x8 kb1 = *(const bf16x8*)qk_ptr(kbase, 16 + lo, hi * 8);
        bf16x8 kb2 = *(const bf16x8*)qk_ptr(kbase, 32 + lo, hi * 8);
        bf16x8 kb3 = *(const bf16x8*)qk_ptr(kbase, 48 + lo, hi * 8);

        // S^T = mfma(K, Q): t[nt][mi], col i = arow+mi*16+lo, row j = nt*16+hi*4+r
        f32x4 t[4][2];
#pragma unroll
        for (int nt = 0; nt < 4; ++nt)
#pragma unroll
            for (int mi = 0; mi < 2; ++mi) t[nt][mi] = (f32x4){0.f, 0.f, 0.f, 0.f};
        t[0][0] = __builtin_amdgcn_mfma_f32_16x16x32_bf16(kb0, qa0, t[0][0], 0, 0, 0);
        t[1][0] = __builtin_amdgcn_mfma_f32_16x16x32_bf16(kb1, qa0, t[1][0], 0, 0, 0);
        t[2][0] = __builtin_amdgcn_mfma_f32_16x16x32_bf16(kb2, qa0, t[2][0], 0, 0, 0);
        t[3][0] = __builtin_amdgcn_mfma_f32_16x16x32_bf16(kb3, qa0, t[3][0], 0, 0, 0);
        t[0][1] = __builtin_amdgcn_mfma_f32_16x16x32_bf16(kb0, qa1, t[0][1], 0, 0, 0);
        t[1][1] = __builtin_amdgcn_mfma_f32_16x16x32_bf16(kb1, qa1, t[1][1], 0, 0, 0);
        t[2][1] = __builtin_amdgcn_mfma_f32_16x16x32_bf16(kb2, qa1, t[2][1], 0, 0, 0);
        t[3][1] = __builtin_amdgcn_mfma_f32_16x16x32_bf16(kb3, qa1, t[3][1], 0, 0, 0);

        if (USE_COMBO) {
#pragma unroll
            for (int mi = 0; mi < 2; ++mi)
#pragma unroll
                for (int nt = 0; nt < 4; ++nt) t[nt][mi] += cv[mi][nt];
        } else {
            const float* mk = mask + (size_t)(b & 63) * 2401;
            const float* rb = rpbx + h * 2401;
#pragma unroll
            for (int nt = 0; nt < 4; ++nt)
#pragma unroll
                for (int mi = 0; mi < 2; ++mi)
#pragma unroll
                    for (int r = 0; r < 4; ++r) {
                        const int i = arow + mi * 16 + lo;       // query
                        const int j = nt * 16 + hi * 4 + r;      // key
                        float sv = t[nt][mi][r];
                        if (j >= 49 || i >= 49) sv = -1e30f;
                        else sv += rb[i * 49 + j] + mk[i * 49 + j];
                        t[nt][mi][r] = sv;
                    }
        }

        // softmax over j: 16 values in-lane + reduce across the 4 hi-groups
#pragma unroll
        for (int mi = 0; mi < 2; ++mi) {
            float m = t[0][mi][0];
#pragma unroll
            for (int nt = 0; nt < 4; ++nt)
#pragma unroll
                for (int r = 0; r < 4; ++r) m = fmaxf(m, t[nt][mi][r]);
            m = fmaxf(m, __shfl_xor(m, 16));
            m = fmaxf(m, __shfl_xor(m, 32));
            float sum = 0.f;
#pragma unroll
            for (int nt = 0; nt < 4; ++nt)
#pragma unroll
                for (int r = 0; r < 4; ++r) {
                    float pv = __expf(t[nt][mi][r] - m);
                    t[nt][mi][r] = pv;
                    sum += pv;
                }
            sum += __shfl_xor(sum, 16);
            sum += __shfl_xor(sum, 32);
            const float inv = 1.0f / sum;
#pragma unroll
            for (int nt = 0; nt < 4; ++nt)
#pragma unroll
                for (int r = 0; r < 4; ++r) t[nt][mi][r] *= inv;
        }

        // PV swapped: O^T = mfma(V^T, P): o[nd][mq], col i = arow+mq*16+lo,
        // row d = nd*16+hi*4+r. P staged per 32-col chunk with bf16x4 stores.
        f32x4 o00 = (f32x4){0.f,0.f,0.f,0.f}, o01 = (f32x4){0.f,0.f,0.f,0.f};
        f32x4 o10 = (f32x4){0.f,0.f,0.f,0.f}, o11 = (f32x4){0.f,0.f,0.f,0.f};
#pragma unroll
        for (int kk = 0; kk < 2; ++kk) {
#pragma unroll
            for (int mi = 0; mi < 2; ++mi)
#pragma unroll
                for (int c = 0; c < 2; ++c) {
                    const int nt = kk * 2 + c;
                    bf16x4 pk;
#pragma unroll
                    for (int r = 0; r < 4; ++r) pk[r] = (bf16)t[nt][mi][r];
                    *(bf16x4*)qk_ptr(qb, arow + mi * 16 + lo, c * 16 + hi * 4) = pk;
                }
            bf16x8 pa0 = *(const bf16x8*)qk_ptr(qb, arow + lo, hi * 8);
            bf16x8 pa1 = *(const bf16x8*)qk_ptr(qb, arow + 16 + lo, hi * 8);
            bf16x8 vb0 = *(const bf16x8*)vt_ptr(&s_vt[h][0],  0 + lo, kk * 32 + hi * 8);
            bf16x8 vb1 = *(const bf16x8*)vt_ptr(&s_vt[h][0], 16 + lo, kk * 32 + hi * 8);
            o00 = __builtin_amdgcn_mfma_f32_16x16x32_bf16(vb0, pa0, o00, 0, 0, 0);
            o01 = __builtin_amdgcn_mfma_f32_16x16x32_bf16(vb0, pa1, o01, 0, 0, 0);
            o10 = __builtin_amdgcn_mfma_f32_16x16x32_bf16(vb1, pa0, o10, 0, 0, 0);
            o11 = __builtin_amdgcn_mfma_f32_16x16x32_bf16(vb1, pa1, o11, 0, 0, 0);
        }

        // ao writes: lane holds 4 consecutive d -> bf16x4 stores into s_x (dead)
        {
            bf16x4 w00, w01, w10, w11;
#pragma unroll
            for (int r = 0; r < 4; ++r) {
                w00[r] = (bf16)o00[r]; w01[r] = (bf16)o01[r];
                w10[r] = (bf16)o10[r]; w11[r] = (bf16)o11[r];
            }
            *(bf16x4*)x_ptr(s_x, arow +  0 + lo, h * 32 +  0 + hi * 4) = w00;
            *(bf16x4*)x_ptr(s_x, arow + 16 + lo, h * 32 +  0 + hi * 4) = w01;
            *(bf16x4*)x_ptr(s_x, arow +  0 + lo, h * 32 + 16 + hi * 4) = w10;
            *(bf16x4*)x_ptr(s_x, arow + 16 + lo, h * 32 + 16 + hi * 4) = w11;
        }
    }
    __syncthreads();                               // barrier 3: ao visible

    // ============ Phase 3: out = ao @ out_w^T + out_b (1 col-tile per wave) ===
    {
        const int o2 = wv * 16 + lo;           // 0..191
        f32x4 facc[4];
#pragma unroll
        for (int mi = 0; mi < 4; ++mi) facc[mi] = (f32x4){0.f, 0.f, 0.f, 0.f};

        bf16x8 fbc = *(const bf16x8*)(out_wb + o2 * 192 + hi * 8);
#pragma unroll
        for (int kk = 0; kk < 6; ++kk) {
            bf16x8 fbn;
            if (kk < 5) fbn = *(const bf16x8*)(out_wb + o2 * 192 + (kk + 1) * 32 + hi * 8);
            bf16x8 fa[4];
#pragma unroll
            for (int mi = 0; mi < 4; ++mi)
                fa[mi] = *(const bf16x8*)x_ptr(s_x, mi * 16 + lo, kk * 32 + hi * 8);
#pragma unroll
            for (int mi = 0; mi < 4; ++mi)
                facc[mi] = __builtin_amdgcn_mfma_f32_16x16x32_bf16(fa[mi], fbc, facc[mi], 0, 0, 0);
            fbc = fbn;
        }

        const float ob = out_b[o2];
        float* ow = out + (size_t)b * 9408;
#pragma unroll
        for (int mi = 0; mi < 4; ++mi)
#pragma unroll
            for (int r = 0; r < 4; ++r) {
                const int n = mi * 16 + hi * 4 + r;
                if (n < 49) ow[n * 192 + o2] = facc[mi][r] + ob;
            }
    }
}

extern "C" void kernel_launch(void* const* d_in, const int* in_sizes, int n_in,
                              void* d_out, int out_size, void* d_ws, size_t ws_size,
                              hipStream_t stream) {
    const float* x      = (const float*)d_in[0];
    const float* mask   = (const float*)d_in[1];
    const float* qkv_w  = (const float*)d_in[2];
    const float* qkv_b  = (const float*)d_in[3];
    const float* out_w  = (const float*)d_in[4];
    const float* out_b  = (const float*)d_in[5];
    const float* rpb    = (const float*)d_in[6];
    float* out          = (float*)d_out;

    char* ws = (char*)d_ws;
    bf16*  qkv_wb = (bf16*)ws;                       // 110592 * 2 = 221184 B
    bf16*  out_wb = (bf16*)(ws + 221184);            //  36864 * 2 =  73728 B
    float* rpbx   = (float*)(ws + 294912);           //  14406 * 4 =  57624 B
    float* combo  = (float*)(ws + 352768);           // 1572864 * 4 = 6291456 B
    const bool use_combo = ws_size >= (size_t)(352768 + 6291456);

    hipLaunchKernelGGL(wmsa_prep, dim3(6144), dim3(256), 0, stream,
                       qkv_w, out_w, rpb, mask, qkv_wb, out_wb, rpbx, combo,
                       use_combo ? 1 : 0);
    if (use_combo)
        hipLaunchKernelGGL(HIP_KERNEL_NAME(wmsa_fused<true>), dim3(4096), dim3(768), 0, stream,
                           x, mask, qkv_b, out_b, qkv_wb, out_wb, rpbx, combo, out);
    else
        hipLaunchKernelGGL(HIP_KERNEL_NAME(wmsa_fused<false>), dim3(4096), dim3(768), 0, stream,
                           x, mask, qkv_b, out_b, qkv_wb, out_wb, rpbx, combo, out);
}

// Round 20
// 257.191 us; speedup vs baseline: 1.2589x; 1.0019x over previous
//
#include <hip/hip_runtime.h>
#include <hip/hip_bf16.h>

typedef __bf16 bf16;
typedef __bf16 bf16x4 __attribute__((ext_vector_type(4)));
typedef __bf16 bf16x8 __attribute__((ext_vector_type(8)));
typedef float f32x4 __attribute__((ext_vector_type(4)));
typedef float floatv4 __attribute__((ext_vector_type(4)));

#define QK_SCALE 0.17677669529663687f

// ---- padded affine LDS addressing (no XOR swizzle) ---------------------------
#define X_LD 200   // x/ao tile [64][200]
#define QK_LD 40   // q/k tiles [64][40]
#define VT_LD 72   // vt tiles [32][72]

__device__ __forceinline__ bf16* x_ptr(bf16* base, int row, int col) {
    return base + row * X_LD + col;
}
__device__ __forceinline__ bf16* qk_ptr(bf16* base, int row, int col) {
    return base + row * QK_LD + col;
}
__device__ __forceinline__ bf16* vt_ptr(bf16* base, int row, int col) {
    return base + row * VT_LD + col;
}

// ---------------- prep: weight bf16 convert + rpb expand + combo table --------
__global__ void wmsa_prep(const float* __restrict__ qkv_w,
                          const float* __restrict__ out_w,
                          const float* __restrict__ rpb_table,
                          const float* __restrict__ mask,
                          bf16* __restrict__ qkv_wb,
                          bf16* __restrict__ out_wb,
                          float* __restrict__ rpbx,
                          float* __restrict__ combo,
                          int build_combo) {
    int t = blockIdx.x * 256 + threadIdx.x;
    if (t < 110592) qkv_wb[t] = (bf16)qkv_w[t];
    if (t < 36864)  out_wb[t] = (bf16)out_w[t];
    if (t < 14406) {
        int h = t / 2401, ij = t % 2401, i = ij / 49, j = ij % 49;
        int ri = (i / 7 - j / 7 + 6) * 13 + (i % 7 - j % 7 + 6);
        rpbx[t] = rpb_table[ri * 6 + h];
    }
    if (build_combo && t < 64 * 6 * 64 * 64) {
        int j = t & 63, i = (t >> 6) & 63, r = t >> 12;
        int h = r % 6, w = r / 6;
        float v = -1e30f;
        if (i < 49 && j < 49) {
            int ri = (i / 7 - j / 7 + 6) * 13 + (i % 7 - j % 7 + 6);
            v = rpb_table[ri * 6 + h] + mask[w * 2401 + i * 49 + j];
        }
        combo[t] = v;
    }
}

// =================== fused kernel: one window per block, 12 waves =============
// r15 + s_setprio(1) isolated around phase-2 MFMA clusters (barrier-free phase
// => wave role diversity => T5's positive regime).
template <bool USE_COMBO>
__global__ __launch_bounds__(768, 3) void wmsa_fused(
    const float* __restrict__ x, const float* __restrict__ mask,
    const float* __restrict__ qkv_b, const float* __restrict__ out_b,
    const bf16* __restrict__ qkv_wb, const bf16* __restrict__ out_wb,
    const float* __restrict__ rpbx, const float* __restrict__ combo,
    float* __restrict__ out)
{
    __shared__ __align__(16) bf16 s_x[64 * X_LD];     // x [64][200]; later ao
    __shared__ __align__(16) bf16 s_qp[6][64 * QK_LD];// q, then P (per head)
    __shared__ __align__(16) bf16 s_k[6][64 * QK_LD]; // k (per head)
    __shared__ __align__(16) bf16 s_vt[6][32 * VT_LD];// v^T

    const int b    = blockIdx.x;
    const int tid  = threadIdx.x;
    const int wv   = tid >> 6;      // 0..11
    const int lane = tid & 63;
    const int lo   = lane & 15;
    const int hi   = lane >> 4;     // 0..3

    const float* xw    = x + (size_t)b * 9408;
    const int    obase = wv * 48;   // 48 qkv output cols per wave
    const int    sec   = wv >> 2;   // 0=q 1=k 2=v (uniform per wave)

    // ============ Phase 0: stage x (fp32 -> bf16) into LDS, zero-padded =======
    {
        const int c0 = tid;                       // rows 0..31
        const int r0s = c0 / 24, cc0 = c0 % 24;
        const float* p0 = xw + r0s * 192 + cc0 * 8;
        floatv4 f0 = *(const floatv4*)p0;
        floatv4 f1 = *(const floatv4*)(p0 + 4);
        bf16x8 v;
        v[0]=(bf16)f0[0]; v[1]=(bf16)f0[1]; v[2]=(bf16)f0[2]; v[3]=(bf16)f0[3];
        v[4]=(bf16)f1[0]; v[5]=(bf16)f1[1]; v[6]=(bf16)f1[2]; v[7]=(bf16)f1[3];
        *(bf16x8*)&s_x[r0s * X_LD + cc0 * 8] = v;

        const int c1 = tid + 768;                 // rows 32..63 (zero >= 49)
        const int r1s = c1 / 24, cc1 = c1 % 24;
        bf16x8 w = {};
        if (r1s < 49) {
            const float* p1 = xw + r1s * 192 + cc1 * 8;
            floatv4 g0 = *(const floatv4*)p1;
            floatv4 g1 = *(const floatv4*)(p1 + 4);
            w[0]=(bf16)g0[0]; w[1]=(bf16)g0[1]; w[2]=(bf16)g0[2]; w[3]=(bf16)g0[3];
            w[4]=(bf16)g1[0]; w[5]=(bf16)g1[1]; w[6]=(bf16)g1[2]; w[7]=(bf16)g1[3];
        }
        *(bf16x8*)&s_x[r1s * X_LD + cc1 * 8] = w;
    }
    __syncthreads();                               // barrier 1: x visible

    // ============ Phase 1: QKV = x @ qkv_w^T + qkv_b (A from LDS, B 2-deep) ===
#pragma unroll 1
    for (int mib = 0; mib < 2; ++mib) {
        f32x4 acc[2][3];
#pragma unroll
        for (int mi = 0; mi < 2; ++mi)
#pragma unroll
            for (int nj = 0; nj < 3; ++nj) acc[mi][nj] = (f32x4){0.f, 0.f, 0.f, 0.f};

        const int r0 = mib * 32 + lo;
        const int r1 = r0 + 16;        // rows >= 49 are zeros in s_x

        auto loadB = [&](bf16x8* dst, int kk) {
#pragma unroll
            for (int nj = 0; nj < 3; ++nj)
                dst[nj] = *(const bf16x8*)(qkv_wb + (obase + nj * 16 + lo) * 192 + kk * 32 + hi * 8);
        };

        bf16x8 b0_[3], b1_[3], b2_[3];
        loadB(b0_, 0);
        loadB(b1_, 1);
#pragma unroll
        for (int kk = 0; kk < 6; ++kk) {
            if (kk < 4) loadB(b2_, kk + 2);
            bf16x8 a0 = *(const bf16x8*)x_ptr(s_x, r0, kk * 32 + hi * 8);
            bf16x8 a1 = *(const bf16x8*)x_ptr(s_x, r1, kk * 32 + hi * 8);
            acc[0][0] = __builtin_amdgcn_mfma_f32_16x16x32_bf16(a0, b0_[0], acc[0][0], 0, 0, 0);
            acc[1][0] = __builtin_amdgcn_mfma_f32_16x16x32_bf16(a1, b0_[0], acc[1][0], 0, 0, 0);
            acc[0][1] = __builtin_amdgcn_mfma_f32_16x16x32_bf16(a0, b0_[1], acc[0][1], 0, 0, 0);
            acc[1][1] = __builtin_amdgcn_mfma_f32_16x16x32_bf16(a1, b0_[1], acc[1][1], 0, 0, 0);
            acc[0][2] = __builtin_amdgcn_mfma_f32_16x16x32_bf16(a0, b0_[2], acc[0][2], 0, 0, 0);
            acc[1][2] = __builtin_amdgcn_mfma_f32_16x16x32_bf16(a1, b0_[2], acc[1][2], 0, 0, 0);
            b0_[0] = b1_[0]; b0_[1] = b1_[1]; b0_[2] = b1_[2];
            b1_[0] = b2_[0]; b1_[1] = b2_[1]; b1_[2] = b2_[2];
        }

        // epilogue: bias + scatter into q / k / v^T LDS tiles
        if (sec < 2) {
#pragma unroll
            for (int nj = 0; nj < 3; ++nj) {
                const int o    = obase + nj * 16 + lo;
                const float bs = qkv_b[o];
                const int oc   = o - sec * 192;
                const int hh   = oc >> 5;
                const int dd   = oc & 31;
                bf16* base = (sec == 0) ? &s_qp[hh][0] : &s_k[hh][0];
#pragma unroll
                for (int mi = 0; mi < 2; ++mi)
#pragma unroll
                    for (int r = 0; r < 4; ++r) {
                        const int n = mib * 32 + mi * 16 + hi * 4 + r;
                        const float v = acc[mi][nj][r] + bs;
                        *qk_ptr(base, n, dd) = (sec == 0) ? (bf16)(v * QK_SCALE) : (bf16)v;
                    }
            }
        } else {
            // v waves: rows n contiguous in r -> vectorized b64 stores into vt
#pragma unroll
            for (int nj = 0; nj < 3; ++nj) {
                const int o    = obase + nj * 16 + lo;
                const float bs = qkv_b[o];
                const int oc   = o - 384;
                const int hh   = oc >> 5;
                const int dd   = oc & 31;
#pragma unroll
                for (int mi = 0; mi < 2; ++mi) {
                    const int n0 = mib * 32 + mi * 16 + hi * 4;
                    bf16x4 pk;
#pragma unroll
                    for (int r = 0; r < 4; ++r) pk[r] = (bf16)(acc[mi][nj][r] + bs);
                    *(bf16x4*)vt_ptr(&s_vt[hh][0], dd, n0) = pk;
                }
            }
        }
    }
    __syncthreads();                               // barrier 2: q/k/vt visible

    // ====== Phase 2: attention, swapped operands, per-wave decoupled ==========
    {
        const int h    = wv >> 1;    // 0..5
        const int arow = (wv & 1) * 32;
        bf16* qb    = &s_qp[h][0];
        bf16* kbase = &s_k[h][0];

        // combo loads: one floatv4 per (mi,nt): 8 dwordx4 instead of 32 dword
        f32x4 cv[2][4];
        if (USE_COMBO) {
            const float* cb = combo + (((size_t)(b & 63) * 6 + h) << 12);
#pragma unroll
            for (int mi = 0; mi < 2; ++mi) {
                const int i = arow + mi * 16 + lo;
#pragma unroll
                for (int nt = 0; nt < 4; ++nt)
                    cv[mi][nt] = *(const floatv4*)(cb + i * 64 + nt * 16 + hi * 4);
            }
        }

        bf16x8 qa0 = *(const bf16x8*)qk_ptr(qb, arow + lo, hi * 8);
        bf16x8 qa1 = *(const bf16x8*)qk_ptr(qb, arow + 16 + lo, hi * 8);
        bf16x8 kb0 = *(const bf16x8*)qk_ptr(kbase,  0 + lo, hi * 8);
        bf16x8 kb1 = *(const bf16x8*)qk_ptr(kbase, 16 + lo, hi * 8);
        bf16x8 kb2 = *(const bf16x8*)qk_ptr(kbase, 32 + lo, hi * 8);
        bf16x8 kb3 = *(const bf16x8*)qk_ptr(kbase, 48 + lo, hi * 8);

        // S^T = mfma(K, Q): t[nt][mi], col i = arow+mi*16+lo, row j = nt*16+hi*4+r
        f32x4 t[4][2];
#pragma unroll
        for (int nt = 0; nt < 4; ++nt)
#pragma unroll
            for (int mi = 0; mi < 2; ++mi) t[nt][mi] = (f32x4){0.f, 0.f, 0.f, 0.f};
        __builtin_amdgcn_s_setprio(1);
        t[0][0] = __builtin_amdgcn_mfma_f32_16x16x32_bf16(kb0, qa0, t[0][0], 0, 0, 0);
        t[1][0] = __builtin_amdgcn_mfma_f32_16x16x32_bf16(kb1, qa0, t[1][0], 0, 0, 0);
        t[2][0] = __builtin_amdgcn_mfma_f32_16x16x32_bf16(kb2, qa0, t[2][0], 0, 0, 0);
        t[3][0] = __builtin_amdgcn_mfma_f32_16x16x32_bf16(kb3, qa0, t[3][0], 0, 0, 0);
        t[0][1] = __builtin_amdgcn_mfma_f32_16x16x32_bf16(kb0, qa1, t[0][1], 0, 0, 0);
        t[1][1] = __builtin_amdgcn_mfma_f32_16x16x32_bf16(kb1, qa1, t[1][1], 0, 0, 0);
        t[2][1] = __builtin_amdgcn_mfma_f32_16x16x32_bf16(kb2, qa1, t[2][1], 0, 0, 0);
        t[3][1] = __builtin_amdgcn_mfma_f32_16x16x32_bf16(kb3, qa1, t[3][1], 0, 0, 0);
        __builtin_amdgcn_s_setprio(0);

        if (USE_COMBO) {
#pragma unroll
            for (int mi = 0; mi < 2; ++mi)
#pragma unroll
                for (int nt = 0; nt < 4; ++nt) t[nt][mi] += cv[mi][nt];
        } else {
            const float* mk = mask + (size_t)(b & 63) * 2401;
            const float* rb = rpbx + h * 2401;
#pragma unroll
            for (int nt = 0; nt < 4; ++nt)
#pragma unroll
                for (int mi = 0; mi < 2; ++mi)
#pragma unroll
                    for (int r = 0; r < 4; ++r) {
                        const int i = arow + mi * 16 + lo;       // query
                        const int j = nt * 16 + hi * 4 + r;      // key
                        float sv = t[nt][mi][r];
                        if (j >= 49 || i >= 49) sv = -1e30f;
                        else sv += rb[i * 49 + j] + mk[i * 49 + j];
                        t[nt][mi][r] = sv;
                    }
        }

        // softmax over j: 16 values in-lane + reduce across the 4 hi-groups
#pragma unroll
        for (int mi = 0; mi < 2; ++mi) {
            float m = t[0][mi][0];
#pragma unroll
            for (int nt = 0; nt < 4; ++nt)
#pragma unroll
                for (int r = 0; r < 4; ++r) m = fmaxf(m, t[nt][mi][r]);
            m = fmaxf(m, __shfl_xor(m, 16));
            m = fmaxf(m, __shfl_xor(m, 32));
            float sum = 0.f;
#pragma unroll
            for (int nt = 0; nt < 4; ++nt)
#pragma unroll
                for (int r = 0; r < 4; ++r) {
                    float pv = __expf(t[nt][mi][r] - m);
                    t[nt][mi][r] = pv;
                    sum += pv;
                }
            sum += __shfl_xor(sum, 16);
            sum += __shfl_xor(sum, 32);
            const float inv = 1.0f / sum;
#pragma unroll
            for (int nt = 0; nt < 4; ++nt)
#pragma unroll
                for (int r = 0; r < 4; ++r) t[nt][mi][r] *= inv;
        }

        // PV swapped: O^T = mfma(V^T, P); P staged per 32-col chunk (bf16x4)
        f32x4 o00 = (f32x4){0.f,0.f,0.f,0.f}, o01 = (f32x4){0.f,0.f,0.f,0.f};
        f32x4 o10 = (f32x4){0.f,0.f,0.f,0.f}, o11 = (f32x4){0.f,0.f,0.f,0.f};
#pragma unroll
        for (int kk = 0; kk < 2; ++kk) {
#pragma unroll
            for (int mi = 0; mi < 2; ++mi)
#pragma unroll
                for (int c = 0; c < 2; ++c) {
                    const int nt = kk * 2 + c;
                    bf16x4 pk;
#pragma unroll
                    for (int r = 0; r < 4; ++r) pk[r] = (bf16)t[nt][mi][r];
                    *(bf16x4*)qk_ptr(qb, arow + mi * 16 + lo, c * 16 + hi * 4) = pk;
                }
            bf16x8 pa0 = *(const bf16x8*)qk_ptr(qb, arow + lo, hi * 8);
            bf16x8 pa1 = *(const bf16x8*)qk_ptr(qb, arow + 16 + lo, hi * 8);
            bf16x8 vb0 = *(const bf16x8*)vt_ptr(&s_vt[h][0],  0 + lo, kk * 32 + hi * 8);
            bf16x8 vb1 = *(const bf16x8*)vt_ptr(&s_vt[h][0], 16 + lo, kk * 32 + hi * 8);
            __builtin_amdgcn_s_setprio(1);
            o00 = __builtin_amdgcn_mfma_f32_16x16x32_bf16(vb0, pa0, o00, 0, 0, 0);
            o01 = __builtin_amdgcn_mfma_f32_16x16x32_bf16(vb0, pa1, o01, 0, 0, 0);
            o10 = __builtin_amdgcn_mfma_f32_16x16x32_bf16(vb1, pa0, o10, 0, 0, 0);
            o11 = __builtin_amdgcn_mfma_f32_16x16x32_bf16(vb1, pa1, o11, 0, 0, 0);
            __builtin_amdgcn_s_setprio(0);
        }

        // ao writes: lane holds 4 consecutive d -> bf16x4 stores into s_x (dead)
        {
            bf16x4 w00, w01, w10, w11;
#pragma unroll
            for (int r = 0; r < 4; ++r) {
                w00[r] = (bf16)o00[r]; w01[r] = (bf16)o01[r];
                w10[r] = (bf16)o10[r]; w11[r] = (bf16)o11[r];
            }
            *(bf16x4*)x_ptr(s_x, arow +  0 + lo, h * 32 +  0 + hi * 4) = w00;
            *(bf16x4*)x_ptr(s_x, arow + 16 + lo, h * 32 +  0 + hi * 4) = w01;
            *(bf16x4*)x_ptr(s_x, arow +  0 + lo, h * 32 + 16 + hi * 4) = w10;
            *(bf16x4*)x_ptr(s_x, arow + 16 + lo, h * 32 + 16 + hi * 4) = w11;
        }
    }
    __syncthreads();                               // barrier 3: ao visible

    // ============ Phase 3: out = ao @ out_w^T + out_b (1 col-tile per wave) ===
    {
        const int o2 = wv * 16 + lo;           // 0..191
        f32x4 facc[4];
#pragma unroll
        for (int mi = 0; mi < 4; ++mi) facc[mi] = (f32x4){0.f, 0.f, 0.f, 0.f};

        bf16x8 fbc = *(const bf16x8*)(out_wb + o2 * 192 + hi * 8);
#pragma unroll
        for (int kk = 0; kk < 6; ++kk) {
            bf16x8 fbn;
            if (kk < 5) fbn = *(const bf16x8*)(out_wb + o2 * 192 + (kk + 1) * 32 + hi * 8);
            bf16x8 fa[4];
#pragma unroll
            for (int mi = 0; mi < 4; ++mi)
                fa[mi] = *(const bf16x8*)x_ptr(s_x, mi * 16 + lo, kk * 32 + hi * 8);
#pragma unroll
            for (int mi = 0; mi < 4; ++mi)
                facc[mi] = __builtin_amdgcn_mfma_f32_16x16x32_bf16(fa[mi], fbc, facc[mi], 0, 0, 0);
            fbc = fbn;
        }

        const float ob = out_b[o2];
        float* ow = out + (size_t)b * 9408;
#pragma unroll
        for (int mi = 0; mi < 4; ++mi)
#pragma unroll
            for (int r = 0; r < 4; ++r) {
                const int n = mi * 16 + hi * 4 + r;
                if (n < 49) ow[n * 192 + o2] = facc[mi][r] + ob;
            }
    }
}

extern "C" void kernel_launch(void* const* d_in, const int* in_sizes, int n_in,
                              void* d_out, int out_size, void* d_ws, size_t ws_size,
                              hipStream_t stream) {
    const float* x      = (const float*)d_in[0];
    const float* mask   = (const float*)d_in[1];
    const float* qkv_w  = (const float*)d_in[2];
    const float* qkv_b  = (const float*)d_in[3];
    const float* out_w  = (const float*)d_in[4];
    const float* out_b  = (const float*)d_in[5];
    const float* rpb    = (const float*)d_in[6];
    float* out          = (float*)d_out;

    char* ws = (char*)d_ws;
    bf16*  qkv_wb = (bf16*)ws;                       // 110592 * 2 = 221184 B
    bf16*  out_wb = (bf16*)(ws + 221184);            //  36864 * 2 =  73728 B
    float* rpbx   = (float*)(ws + 294912);           //  14406 * 4 =  57624 B
    float* combo  = (float*)(ws + 352768);           // 1572864 * 4 = 6291456 B
    const bool use_combo = ws_size >= (size_t)(352768 + 6291456);

    hipLaunchKernelGGL(wmsa_prep, dim3(6144), dim3(256), 0, stream,
                       qkv_w, out_w, rpb, mask, qkv_wb, out_wb, rpbx, combo,
                       use_combo ? 1 : 0);
    if (use_combo)
        hipLaunchKernelGGL(HIP_KERNEL_NAME(wmsa_fused<true>), dim3(4096), dim3(768), 0, stream,
                           x, mask, qkv_b, out_b, qkv_wb, out_wb, rpbx, combo, out);
    else
        hipLaunchKernelGGL(HIP_KERNEL_NAME(wmsa_fused<false>), dim3(4096), dim3(768), 0, stream,
                           x, mask, qkv_b, out_b, qkv_wb, out_wb, rpbx, combo, out);
}